// Round 6
// baseline (1032.966 us; speedup 1.0000x reference)
//
#include <hip/hip_runtime.h>
#include <stdint.h>

#define HD   128
#define ED   100
#define VD   1000
#define FDV  512
#define NS   512
#define TT   64
#define MT   (NS*TT)   // 32768

typedef __attribute__((ext_vector_type(8))) short  short8;
typedef __attribute__((ext_vector_type(4))) float  f32x4;

typedef const __attribute__((address_space(1))) uint16_t* gas_u16;
typedef __attribute__((address_space(3))) uint16_t*       las_u16;

__device__ __forceinline__ float blo(uint32_t u){ return __uint_as_float(u << 16); }
__device__ __forceinline__ float bhi(uint32_t u){ return __uint_as_float(u & 0xffff0000u); }
__device__ __forceinline__ uint16_t f2bf(float f){
  uint32_t x = __float_as_uint(f);
  return (uint16_t)((x + 0x7fffu + ((x >> 16) & 1u)) >> 16);
}
__device__ __forceinline__ float sigf(float x){ return 1.f/(1.f+__expf(-x)); }
__device__ __forceinline__ float ftanh(float x){
  float ax = fabsf(x);
  float e = __expf(-2.f*ax);
  float t = (1.f - e) / (1.f + e);
  return copysignf(t, x);
}
// LDS-only barrier: do NOT drain vmcnt (keeps prefetch loads / stores in flight).
__device__ __forceinline__ void lds_barrier(){
  asm volatile("s_waitcnt lgkmcnt(0)" ::: "memory");
  __builtin_amdgcn_s_barrier();
}

// ---------------- weight/emb conversion (f32 -> bf16, padded) ----------------
struct ConvJob { const float* s; uint16_t* d; int R, R0, C, Cp; };
struct ConvJobs { ConvJob j[12]; };

__global__ void k_convert(ConvJobs jobs){
  int stride = gridDim.x * blockDim.x;
  int tid0 = blockIdx.x * blockDim.x + threadIdx.x;
  for (int ji = 0; ji < 12; ++ji){
    const ConvJob jb = jobs.j[ji];
    int total = jb.R * jb.Cp;
    for (int i = tid0; i < total; i += stride){
      int r = i / jb.Cp, c = i - r*jb.Cp;
      float v = (r < jb.R0 && c < jb.C) ? jb.s[(size_t)r*jb.C + c] : 0.f;
      jb.d[i] = f2bf(v);
    }
  }
}

// ---------------- bf16 MFMA GEMM: global_load_lds staging, optional row-gather ----
// C[M,N] = A[M,K] @ W[Nb,K]^T + bias, 128x128 tile, BK=32, linear LDS.
// tok != null: A-row m is gathered from A[tok[m]] (embedding lookup fused).
// MODE 0: f32 out; 2: f32 out with t>=lens[n] row masking;
// MODE 3: bf16 out remapped to LSTM block layout [n/16][t][16][512] (N must be 512).
template<int MODE>
__global__ __launch_bounds__(256) void k_gemm(
    const uint16_t* __restrict__ A, const uint16_t* __restrict__ W,
    const float* __restrict__ bias, void* __restrict__ out,
    int N, int K, const int* __restrict__ lens, const int* __restrict__ tok)
{
  __shared__ __align__(16) uint16_t lsA[128][32];
  __shared__ __align__(16) uint16_t lsB[128][32];
  const int tid = threadIdx.x;
  const int n0 = blockIdx.x * 128, m0 = blockIdx.y * 128;
  const int l = tid & 63, w = tid >> 6;
  const int wm = (w >> 1) * 64, wn = (w & 1) * 64;
  const int fr = l & 15, fo = (l >> 4) * 8;
  const int srow = w*16 + (l >> 2);
  const int sce  = (l & 3) * 8;
  const int ar0 = m0 + srow, ar1 = m0 + 64 + srow;
  const size_t ab0 = (tok ? (size_t)tok[ar0] : (size_t)ar0) * K;
  const size_t ab1 = (tok ? (size_t)tok[ar1] : (size_t)ar1) * K;
  f32x4 acc[4][4] = {};
  for (int kt = 0; kt < K; kt += 32) {
    {
      __builtin_amdgcn_global_load_lds(
          (gas_u16)(A + ab0 + kt + sce),
          (las_u16)(&lsA[0][0] + w*512), 16, 0, 0);
      __builtin_amdgcn_global_load_lds(
          (gas_u16)(W + (size_t)(n0 + srow) * K + kt + sce),
          (las_u16)(&lsB[0][0] + w*512), 16, 0, 0);
      __builtin_amdgcn_global_load_lds(
          (gas_u16)(A + ab1 + kt + sce),
          (las_u16)(&lsA[0][0] + w*512 + 2048), 16, 0, 0);
      __builtin_amdgcn_global_load_lds(
          (gas_u16)(W + (size_t)(n0 + 64 + srow) * K + kt + sce),
          (las_u16)(&lsB[0][0] + w*512 + 2048), 16, 0, 0);
    }
    __syncthreads();
    short8 af[4], bfv[4];
    #pragma unroll
    for (int i = 0; i < 4; ++i) af[i]  = *(const short8*)(&lsA[wm + i*16 + fr][fo]);
    #pragma unroll
    for (int j = 0; j < 4; ++j) bfv[j] = *(const short8*)(&lsB[wn + j*16 + fr][fo]);
    #pragma unroll
    for (int i = 0; i < 4; ++i)
      #pragma unroll
      for (int j = 0; j < 4; ++j)
        acc[i][j] = __builtin_amdgcn_mfma_f32_16x16x32_bf16(af[i], bfv[j], acc[i][j], 0, 0, 0);
    __syncthreads();
  }
  const int r0 = (l >> 4) * 4, cc = l & 15;
  #pragma unroll
  for (int j = 0; j < 4; ++j) {
    int col = n0 + wn + j*16 + cc;
    if (col >= N) continue;
    float bv = bias[col];
    #pragma unroll
    for (int i = 0; i < 4; ++i) {
      #pragma unroll
      for (int r = 0; r < 4; ++r) {
        int row = m0 + wm + i*16 + r0 + r;
        float v = acc[i][j][r] + bv;
        if (MODE == 3) {
          int t = row & 63, n = row >> 6;
          size_t prow = ((size_t)(n >> 4)*64 + (size_t)t)*16 + (n & 15);
          ((uint16_t*)out)[prow * 512 + col] = f2bf(v);
        } else if (MODE == 2) {
          int t = row & 63, n = row >> 6;
          if (t >= lens[n]) v = 0.f;
          ((float*)out)[(size_t)row * N + col] = v;
        } else {
          ((float*)out)[(size_t)row * N + col] = v;
        }
      }
    }
  }
}

// ---------------- fused 2-layer MFMA LSTM recurrence (1-step pipeline) ----------
// Block = 16 samples, 8 waves. Per step t in [0,TT]:
//   L0 (t<TT):  z0 = Whh0·h0[t-1] + X[t]          -> h0[t]   (LDS only)
//   L1 (t>0):   z1 = Wih1·h0[t-1] + Whh1·h1[t-2] + b1 -> h1[t-1] (LDS + global)
// hb0: read slot (t+1)&1, write t&1.  hb1: read slot t&1, write (t+1)&1.
// One lgkm-only barrier per step; X prefetch reuses xv regs across steps.
__global__ __launch_bounds__(512) void k_lstm2(
    const uint16_t* __restrict__ X,      // [NS/16][TT][16][512] = x@Wih0^T + b0
    const uint16_t* __restrict__ Whh0,   // [512][128] bf16
    const uint16_t* __restrict__ Wih1,   // [512][128] bf16
    const uint16_t* __restrict__ Whh1,   // [512][128] bf16
    const float* __restrict__ B1,        // [512] f32
    const float* __restrict__ h0i, const float* __restrict__ c0i,  // [NS][128] or null
    const float* __restrict__ h1i, const float* __restrict__ c1i,  // [NS][128] or null
    uint16_t* __restrict__ hout,         // [MT][128] bf16: layer-1 h (m = n*TT+t)
    float* __restrict__ h0f, float* __restrict__ c0f,              // [NS][128] or null
    float* __restrict__ h1f, float* __restrict__ c1f)
{
  __shared__ __align__(16) uint16_t hb0[2][16][136];
  __shared__ __align__(16) uint16_t hb1[2][16][136];
  const int n0 = blockIdx.x * 16;
  const int w = threadIdx.x >> 6, l = threadIdx.x & 63;
  const int s = l & 15;
  const int hi4 = l >> 4;
  const int j0 = w*16 + hi4*4;

  // weight fragments (A-operand): rows of each gate block, K-chunks
  short8 w0fr[4][4], wi1fr[4][4], wh1fr[4][4];
  #pragma unroll
  for (int g = 0; g < 4; ++g)
    #pragma unroll
    for (int kk = 0; kk < 4; ++kk) {
      const size_t ro = (size_t)(g*128 + w*16 + s)*128 + kk*32 + hi4*8;
      w0fr[g][kk]  = *(const short8*)(Whh0 + ro);
      wi1fr[g][kk] = *(const short8*)(Wih1 + ro);
      wh1fr[g][kk] = *(const short8*)(Whh1 + ro);
    }
  f32x4 b1v[4];
  #pragma unroll
  for (int g = 0; g < 4; ++g) b1v[g] = *(const f32x4*)(B1 + g*128 + j0);

  // state init
  f32x4 cst0 = {0.f,0.f,0.f,0.f}, cst1 = {0.f,0.f,0.f,0.f};
  if (c0i) cst0 = *(const f32x4*)(c0i + (size_t)(n0+s)*128 + j0);
  if (c1i) cst1 = *(const f32x4*)(c1i + (size_t)(n0+s)*128 + j0);
  {
    uint16_t a[4] = {0,0,0,0}, b[4] = {0,0,0,0};
    if (h0i) {
      float4 hv = *(const float4*)(h0i + (size_t)(n0+s)*128 + j0);
      a[0]=f2bf(hv.x); a[1]=f2bf(hv.y); a[2]=f2bf(hv.z); a[3]=f2bf(hv.w);
    }
    if (h1i) {
      float4 hv = *(const float4*)(h1i + (size_t)(n0+s)*128 + j0);
      b[0]=f2bf(hv.x); b[1]=f2bf(hv.y); b[2]=f2bf(hv.z); b[3]=f2bf(hv.w);
    }
    *(uint2*)(&hb0[1][s][j0]) = *(const uint2*)a;   // read at t=0 (slot (0+1)&1 = 1)
    *(uint2*)(&hb1[1][s][j0]) = *(const uint2*)b;   // read at t=1 (slot 1&1 = 1)
  }
  __syncthreads();

  const uint16_t* Xp = X + (size_t)blockIdx.x * TT * 8192 + s*512 + j0;
  uint16_t* hop = hout + (size_t)(n0+s)*TT*HD + j0;

  uint2 xv[4];
  #pragma unroll
  for (int g = 0; g < 4; ++g) xv[g] = *(const uint2*)(Xp + g*128);   // X[0]

  for (int t = 0; t <= TT; ++t) {
    const int ra = (t+1)&1, wa = t&1;
    // shared B-frag: h0[t-1] (serves Whh0·h0 and Wih1·h0)
    short8 bfr0[4];
    #pragma unroll
    for (int kk = 0; kk < 4; ++kk)
      bfr0[kk] = *(const short8*)(&hb0[ra][s][kk*32 + hi4*8]);

    // ---- L1 MFMA (t>0): acc1 = Wih1·h0[t-1] + Whh1·h1[t-2] ----
    f32x4 acc1[4] = {{0,0,0,0},{0,0,0,0},{0,0,0,0},{0,0,0,0}};
    if (t > 0) {
      short8 bfr1[4];
      #pragma unroll
      for (int kk = 0; kk < 4; ++kk)
        bfr1[kk] = *(const short8*)(&hb1[wa][s][kk*32 + hi4*8]);
      #pragma unroll
      for (int kk = 0; kk < 4; ++kk)
        #pragma unroll
        for (int g = 0; g < 4; ++g)
          acc1[g] = __builtin_amdgcn_mfma_f32_16x16x32_bf16(wh1fr[g][kk], bfr1[kk], acc1[g], 0, 0, 0);
      #pragma unroll
      for (int kk = 0; kk < 4; ++kk)
        #pragma unroll
        for (int g = 0; g < 4; ++g)
          acc1[g] = __builtin_amdgcn_mfma_f32_16x16x32_bf16(wi1fr[g][kk], bfr0[kk], acc1[g], 0, 0, 0);
    }
    // ---- L0 MFMA (t<TT): acc0 = Whh0·h0[t-1] ----
    f32x4 acc0[4] = {{0,0,0,0},{0,0,0,0},{0,0,0,0},{0,0,0,0}};
    if (t < TT) {
      #pragma unroll
      for (int kk = 0; kk < 4; ++kk)
        #pragma unroll
        for (int g = 0; g < 4; ++g)
          acc0[g] = __builtin_amdgcn_mfma_f32_16x16x32_bf16(w0fr[g][kk], bfr0[kk], acc0[g], 0, 0, 0);
    }
    // ---- L1 gates -> h1[t-1] ----
    if (t > 0) {
      uint16_t hb[4];
      #pragma unroll
      for (int r = 0; r < 4; ++r) {
        float zi = acc1[0][r] + b1v[0][r];
        float zf = acc1[1][r] + b1v[1][r];
        float zg = acc1[2][r] + b1v[2][r];
        float zo = acc1[3][r] + b1v[3][r];
        float cn = sigf(zf) * cst1[r] + sigf(zi) * ftanh(zg);
        float h  = sigf(zo) * ftanh(cn);
        cst1[r] = cn;
        hb[r] = f2bf(h);
      }
      *(uint2*)(&hb1[ra][s][j0]) = *(const uint2*)hb;
      *(uint2*)(hop + (size_t)(t-1)*HD) = *(const uint2*)hb;
    }
    // ---- L0 gates -> h0[t] (consumes xv), then prefetch X[t+1] into xv ----
    if (t < TT) {
      uint16_t hb[4];
      #pragma unroll
      for (int r = 0; r < 4; ++r) {
        uint32_t wi = (r & 2) ? xv[0].y : xv[0].x;
        uint32_t wf = (r & 2) ? xv[1].y : xv[1].x;
        uint32_t wg = (r & 2) ? xv[2].y : xv[2].x;
        uint32_t wo = (r & 2) ? xv[3].y : xv[3].x;
        float zi = acc0[0][r] + ((r & 1) ? bhi(wi) : blo(wi));
        float zf = acc0[1][r] + ((r & 1) ? bhi(wf) : blo(wf));
        float zg = acc0[2][r] + ((r & 1) ? bhi(wg) : blo(wg));
        float zo = acc0[3][r] + ((r & 1) ? bhi(wo) : blo(wo));
        float cn = sigf(zf) * cst0[r] + sigf(zi) * ftanh(zg);
        float h  = sigf(zo) * ftanh(cn);
        cst0[r] = cn;
        hb[r] = f2bf(h);
      }
      *(uint2*)(&hb0[wa][s][j0]) = *(const uint2*)hb;
      if (t + 1 < TT) {
        const uint16_t* Xn = Xp + (size_t)(t+1)*8192;
        #pragma unroll
        for (int g = 0; g < 4; ++g) xv[g] = *(const uint2*)(Xn + g*128);
      }
    }
    lds_barrier();
  }

  // finals (encoder): h0[63] in hb0[1], h1[63] in hb1[1]; c in regs.
  if (h0f) {
    uint2 a = *(const uint2*)(&hb0[1][s][j0]);
    uint2 b = *(const uint2*)(&hb1[1][s][j0]);
    const uint16_t* ap = (const uint16_t*)&a;
    const uint16_t* bp = (const uint16_t*)&b;
    float4 h0v = make_float4(blo(ap[0]), blo(ap[1]), blo(ap[2]), blo(ap[3]));
    float4 h1v = make_float4(blo(bp[0]), blo(bp[1]), blo(bp[2]), blo(bp[3]));
    *(float4*)(h0f + (size_t)(n0+s)*128 + j0) = h0v;
    *(float4*)(h1f + (size_t)(n0+s)*128 + j0) = h1v;
    *(f32x4*)(c0f + (size_t)(n0+s)*128 + j0) = cst0;
    *(f32x4*)(c1f + (size_t)(n0+s)*128 + j0) = cst1;
  }
}

// ---------------- fused attention + feat assembly ----------------
__global__ __launch_bounds__(256) void k_attn(
    const float* __restrict__ keys,     // [MT][128] f32
    const uint16_t* __restrict__ h1,    // [MT][128] bf16
    const uint16_t* __restrict__ imgb,  // [512] bf16
    uint16_t* __restrict__ feat)        // [MT][896]
{
  __shared__ float ks[64][129];
  __shared__ float ps[4][64];
  const int n = blockIdx.x;
  for (int i = threadIdx.x; i < 64*128; i += 256)
    ks[i >> 7][i & 127] = keys[(size_t)n*8192 + i];
  const int w = threadIdx.x >> 6, l = threadIdx.x & 63;
  uint32_t hd = 0;
  if (n > 0) hd = ((const uint32_t*)(h1 + ((size_t)(n-1)*64 + 63)*128))[l];
  const uint4 iv = ((const uint4*)imgb)[l];
  __syncthreads();
  for (int tt = 0; tt < 16; ++tt) {
    const int t = tt*4 + w;
    const size_t m = (size_t)n*64 + t;
    const uint4* hp = (const uint4*)(h1 + m*128);
    float s = 0.f;
    #pragma unroll
    for (int k = 0; k < 16; ++k) {
      uint4 hv = hp[k];
      s += ks[l][8*k+0]*blo(hv.x) + ks[l][8*k+1]*bhi(hv.x)
         + ks[l][8*k+2]*blo(hv.y) + ks[l][8*k+3]*bhi(hv.y)
         + ks[l][8*k+4]*blo(hv.z) + ks[l][8*k+5]*bhi(hv.z)
         + ks[l][8*k+6]*blo(hv.w) + ks[l][8*k+7]*bhi(hv.w);
    }
    float mx = s;
    #pragma unroll
    for (int o = 32; o; o >>= 1) mx = fmaxf(mx, __shfl_xor(mx, o));
    float p = __expf(s - mx);
    float sm = p;
    #pragma unroll
    for (int o = 32; o; o >>= 1) sm += __shfl_xor(sm, o);
    p /= sm;
    ps[w][l] = p;
    float c0 = 0.f, c1 = 0.f;
    #pragma unroll
    for (int q = 0; q < 64; ++q) {
      float pq = ps[w][q];
      c0 += pq * ks[q][l];
      c1 += pq * ks[q][l + 64];
    }
    uint16_t* fr_ = feat + m*896;
    ((uint32_t*)fr_)[l] = ((const uint32_t*)(h1 + m*128))[l];  // h1 copy
    fr_[128 + l] = f2bf(c0);
    fr_[192 + l] = f2bf(c1);
    ((uint32_t*)(fr_ + 256))[l] = hd;                          // history
    ((uint4*)(fr_ + 384))[l] = iv;                             // img
  }
}

extern "C" void kernel_launch(void* const* d_in, const int* in_sizes, int n_in,
                              void* d_out, int out_size, void* d_ws, size_t ws_size,
                              hipStream_t stream) {
  const int*   questions = (const int*)d_in[0];
  const int*   answers   = (const int*)d_in[1];
  const int*   lens      = (const int*)d_in[2];
  const float* img       = (const float*)d_in[3];
  const float* emb       = (const float*)d_in[4];
  const float* eWih0 = (const float*)d_in[5],  *eWhh0 = (const float*)d_in[6],  *eB0 = (const float*)d_in[7];
  const float* eWih1 = (const float*)d_in[8],  *eWhh1 = (const float*)d_in[9],  *eB1 = (const float*)d_in[10];
  const float* dWih0 = (const float*)d_in[11], *dWhh0 = (const float*)d_in[12], *dB0 = (const float*)d_in[13];
  const float* dWih1 = (const float*)d_in[14], *dWhh1 = (const float*)d_in[15], *dB1 = (const float*)d_in[16];
  const float* Wk   = (const float*)d_in[17], *bk   = (const float*)d_in[18];
  const float* Wout = (const float*)d_in[19], *bout = (const float*)d_in[20];

  char* ws = (char*)d_ws;
  size_t off = 0;
  auto alloc = [&](size_t n)->char* {
    char* p = ws + off; off += (n + 255) & ~(size_t)255; return p;
  };
  uint16_t* embP  = (uint16_t*)alloc((size_t)VD*128*2);
  uint16_t* wih0e = (uint16_t*)alloc(512*128*2);
  uint16_t* whh0e = (uint16_t*)alloc(512*128*2);
  uint16_t* wih1e = (uint16_t*)alloc(512*128*2);
  uint16_t* whh1e = (uint16_t*)alloc(512*128*2);
  uint16_t* wih0d = (uint16_t*)alloc(512*128*2);
  uint16_t* whh0d = (uint16_t*)alloc(512*128*2);
  uint16_t* wih1d = (uint16_t*)alloc(512*128*2);
  uint16_t* whh1d = (uint16_t*)alloc(512*128*2);
  uint16_t* wkb   = (uint16_t*)alloc(128*128*2);
  uint16_t* woutb = (uint16_t*)alloc((size_t)1024*896*2);   // padded to 1024 rows
  uint16_t* imgb  = (uint16_t*)alloc(512*2);
  uint16_t* Xbuf  = (uint16_t*)alloc((size_t)MT*512*2);
  uint16_t* h1b   = (uint16_t*)alloc((size_t)MT*128*2);
  float*    keysf = (float*)   alloc((size_t)MT*128*4);
  uint16_t* feat  = (uint16_t*)alloc((size_t)MT*896*2);
  float* eh0 = (float*)alloc(NS*128*4);
  float* ec0 = (float*)alloc(NS*128*4);
  float* eh1 = (float*)alloc(NS*128*4);
  float* ec1 = (float*)alloc(NS*128*4);
  if (off > ws_size) return;  // workspace too small; fail visibly

  ConvJobs jobs;
  jobs.j[0]  = {emb,   embP,  VD,  VD,  ED,  128};
  jobs.j[1]  = {eWih0, wih0e, 512, 512, ED,  128};
  jobs.j[2]  = {eWhh0, whh0e, 512, 512, 128, 128};
  jobs.j[3]  = {eWih1, wih1e, 512, 512, 128, 128};
  jobs.j[4]  = {eWhh1, whh1e, 512, 512, 128, 128};
  jobs.j[5]  = {dWih0, wih0d, 512, 512, ED,  128};
  jobs.j[6]  = {dWhh0, whh0d, 512, 512, 128, 128};
  jobs.j[7]  = {dWih1, wih1d, 512, 512, 128, 128};
  jobs.j[8]  = {dWhh1, whh1d, 512, 512, 128, 128};
  jobs.j[9]  = {Wk,    wkb,   128, 128, 128, 128};
  jobs.j[10] = {Wout,  woutb, 1024, VD, 896, 896};
  jobs.j[11] = {img,   imgb,  1,   1,   512, 512};
  hipLaunchKernelGGL(k_convert, dim3(1024), dim3(256), 0, stream, jobs);

  // ---- encoder: layer-0 input GEMM (emb gather fused) + fused 2-layer recurrence ----
  hipLaunchKernelGGL(k_gemm<3>, dim3(4, MT/128), dim3(256), 0, stream, embP, wih0e, eB0, Xbuf, 512, 128, nullptr, questions);
  hipLaunchKernelGGL(k_lstm2, dim3(NS/16), dim3(512), 0, stream,
                     Xbuf, whh0e, wih1e, whh1e, eB1,
                     (const float*)nullptr, (const float*)nullptr, (const float*)nullptr, (const float*)nullptr,
                     h1b, eh0, ec0, eh1, ec1);
  hipLaunchKernelGGL(k_gemm<0>, dim3(1, MT/128), dim3(256), 0, stream, h1b, wkb, bk, keysf, 128, 128, nullptr, nullptr);

  // ---- decoder: same, seeded with encoder finals ----
  hipLaunchKernelGGL(k_gemm<3>, dim3(4, MT/128), dim3(256), 0, stream, embP, wih0d, dB0, Xbuf, 512, 128, nullptr, answers);
  hipLaunchKernelGGL(k_lstm2, dim3(NS/16), dim3(512), 0, stream,
                     Xbuf, whh0d, wih1d, whh1d, dB1,
                     eh0, ec0, eh1, ec1,
                     h1b, (float*)nullptr, (float*)nullptr, (float*)nullptr, (float*)nullptr);

  // ---- fused attention/feat + output projection ----
  hipLaunchKernelGGL(k_attn, dim3(NS), dim3(256), 0, stream, keysf, h1b, imgb, feat);
  hipLaunchKernelGGL(k_gemm<2>, dim3(8, MT/128), dim3(256), 0, stream, feat, woutb, bout, d_out, VD, 896, lens, nullptr);
}